// Round 1
// baseline (155.681 us; speedup 1.0000x reference)
//
#include <hip/hip_runtime.h>

#define HH 512
#define IND 13
#define NN 2048
#define RR 256
#define WDIM 7168      // (13+1)*512
#define W1DIM 6656     // 13*512
#define NTHREADS 256
#define N_PER_THREAD 4
#define N_TILE (NTHREADS * N_PER_THREAD)  // 1024

// -0.5 * log(2*pi)
#define NEG_HALF_LOG_2PI (-0.91893853320467274f)

__global__ __launch_bounds__(NTHREADS, 2)
void ffrelu_loglik_kernel(const float* __restrict__ x,
                          const float* __restrict__ y,
                          const float* __restrict__ w,
                          float* __restrict__ out) {
    // Per-h row of 16 floats: [w1[h][0..12], w2[h], pad, pad] -> 4x float4 reads
    __shared__ float lds[HH * 16];  // 32 KB

    const int r = blockIdx.y;
    const int n_base = blockIdx.x * N_TILE;
    const int tid = threadIdx.x;

    // ---- stage w1[r] (6656 floats) into padded LDS rows ----
    const float* wr = w + (size_t)r * WDIM;
    for (int g = tid; g < W1DIM; g += NTHREADS) {
        int h = g / IND;            // compiler emits magic-mul
        int i = g - h * IND;
        lds[h * 16 + i] = wr[g];
    }
    // ---- stage w2[r] (512 floats) into pad slot 13 ----
    for (int g = tid; g < HH; g += NTHREADS) {
        lds[g * 16 + 13] = wr[W1DIM + g];
    }
    __syncthreads();

    // ---- load this thread's 4 x-rows into registers ----
    const int n0 = n_base + tid * N_PER_THREAD;
    float xr[N_PER_THREAD][IND];
    float mu[N_PER_THREAD];
#pragma unroll
    for (int j = 0; j < N_PER_THREAD; ++j) {
        const float* xp = x + (size_t)(n0 + j) * IND;
#pragma unroll
        for (int i = 0; i < IND; ++i) xr[j][i] = xp[i];
        mu[j] = 0.0f;
    }

    const float4* ldsv = (const float4*)lds;

    // ---- main loop over hidden units ----
#pragma unroll 2
    for (int h = 0; h < HH; ++h) {
        float4 a = ldsv[h * 4 + 0];   // w1 i=0..3   (broadcast ds_read_b128)
        float4 b = ldsv[h * 4 + 1];   // w1 i=4..7
        float4 c = ldsv[h * 4 + 2];   // w1 i=8..11
        float4 d = ldsv[h * 4 + 3];   // d.x = w1 i=12, d.y = w2[h]
        const float w2v = d.y;
#pragma unroll
        for (int j = 0; j < N_PER_THREAD; ++j) {
            float s;
            s = a.x * xr[j][0];
            s = fmaf(a.y, xr[j][1], s);
            s = fmaf(a.z, xr[j][2], s);
            s = fmaf(a.w, xr[j][3], s);
            s = fmaf(b.x, xr[j][4], s);
            s = fmaf(b.y, xr[j][5], s);
            s = fmaf(b.z, xr[j][6], s);
            s = fmaf(b.w, xr[j][7], s);
            s = fmaf(c.x, xr[j][8], s);
            s = fmaf(c.y, xr[j][9], s);
            s = fmaf(c.z, xr[j][10], s);
            s = fmaf(c.w, xr[j][11], s);
            s = fmaf(d.x, xr[j][12], s);
            s = fmaxf(s, 0.0f);                 // relu
            mu[j] = fmaf(s, w2v, mu[j]);        // mu += hidden * w2[h]
        }
    }

    // ---- epilogue: Normal(mu, 1) log-prob, coalesced float4 store ----
    float4 res;
    float* resp = &res.x;
#pragma unroll
    for (int j = 0; j < N_PER_THREAD; ++j) {
        float resid = y[n0 + j] - mu[j];
        resp[j] = fmaf(-0.5f * resid, resid, NEG_HALF_LOG_2PI);
    }
    *(float4*)(out + (size_t)r * NN + n0) = res;
}

extern "C" void kernel_launch(void* const* d_in, const int* in_sizes, int n_in,
                              void* d_out, int out_size, void* d_ws, size_t ws_size,
                              hipStream_t stream) {
    const float* x = (const float*)d_in[0];   // [N, 13]
    const float* y = (const float*)d_in[1];   // [N, 1]
    const float* w = (const float*)d_in[2];   // [R, 7168]
    float* out = (float*)d_out;               // [R, N]

    dim3 grid(NN / N_TILE, RR);   // (2, 256)
    dim3 block(NTHREADS);
    ffrelu_loglik_kernel<<<grid, block, 0, stream>>>(x, y, w, out);
}

// Round 2
// 110.648 us; speedup vs baseline: 1.4070x; 1.4070x over previous
//
#include <hip/hip_runtime.h>

#define HH 512
#define IND 13
#define NN 2048
#define RR 256
#define WDIM 7168      // (13+1)*512
#define W1DIM 6656     // 13*512
#define NTHREADS 256
#define NEG_HALF_LOG_2PI (-0.91893853320467274f)

typedef __attribute__((ext_vector_type(8))) short short8;   // 8 bf16 (4 VGPRs) MFMA A/B frag
typedef __attribute__((ext_vector_type(4))) float f32x4;    // MFMA C/D frag

// fp32 -> bf16 round-to-nearest-even (bit pattern)
__device__ __forceinline__ short f2bf(float f) {
    unsigned u = __float_as_uint(f);
    u += 0x7fffu + ((u >> 16) & 1u);
    return (short)(u >> 16);
}
__device__ __forceinline__ float bf2f(short s) {
    return __uint_as_float(((unsigned)(unsigned short)s) << 16);
}

// Per block: one r, 512 n (4 waves x 128 n). Per wave: 32 h-tiles x 8 n-tiles of
// 16x16x32 bf16 MFMA, hidden stays in C-frags, relu+w2-dot in fp32 VALU.
// K packing: A = [w1(13) | w1(13) | 0(6)], B = [x_hi(13) | x_lo(13) | 0(6)]
// => hidden = w1_bf16 . x_fp32 (x split exact); only w1 carries bf16 rounding.
__global__ __launch_bounds__(NTHREADS, 3)
void ffrelu_mfma_kernel(const float* __restrict__ x,
                        const float* __restrict__ y,
                        const float* __restrict__ w,
                        float* __restrict__ out) {
    // w1 rows: 32 bf16 k-slots + 8 pad shorts -> stride 40 shorts (80 B, bank-uniform)
    __shared__ short Als[HH * 40];   // 40 KB
    __shared__ float w2s[HH];        // 2 KB, kept fp32

    const int tid = threadIdx.x;
    const int r = blockIdx.y;
    const int wave = tid >> 6;
    const int lane = tid & 63;
    const int m = lane & 15;        // MFMA row/col index within 16
    const int q = lane >> 4;        // quad 0..3

    const float* wr = w + (size_t)r * WDIM;

    // ---- zero A (k-pad slots 26..31 must be 0), then stage w1 (bf16, k-duplicated) + w2 (fp32) ----
    int* Ai = (int*)Als;
    for (int g = tid; g < HH * 20; g += NTHREADS) Ai[g] = 0;
    __syncthreads();
    for (int g = tid; g < W1DIM; g += NTHREADS) {
        int h = g / IND;
        int i = g - h * IND;
        short b = f2bf(wr[g]);
        Als[h * 40 + i] = b;        // k = i       (pairs with x_hi)
        Als[h * 40 + 13 + i] = b;   // k = 13 + i  (pairs with x_lo)
    }
    for (int g = tid; g < HH; g += NTHREADS) w2s[g] = wr[W1DIM + g];
    __syncthreads();

    // ---- build 8 B-frags from x (hi/lo split), register-resident for whole kernel ----
    const int nb = blockIdx.x * 512 + wave * 128;
    short8 bfrag[8];
#pragma unroll
    for (int nt = 0; nt < 8; ++nt) {
        const float* xp = x + (size_t)(nb + nt * 16 + m) * IND;
        float v[13]; short hs[13], ls[13];
#pragma unroll
        for (int i = 0; i < 13; ++i) {
            v[i] = xp[i];
            hs[i] = f2bf(v[i]);
            ls[i] = f2bf(v[i] - bf2f(hs[i]));
        }
        short8 b;
        if (q == 0) {
            b[0]=hs[0]; b[1]=hs[1]; b[2]=hs[2]; b[3]=hs[3];
            b[4]=hs[4]; b[5]=hs[5]; b[6]=hs[6]; b[7]=hs[7];
        } else if (q == 1) {
            b[0]=hs[8]; b[1]=hs[9]; b[2]=hs[10]; b[3]=hs[11];
            b[4]=hs[12]; b[5]=ls[0]; b[6]=ls[1]; b[7]=ls[2];
        } else if (q == 2) {
            b[0]=ls[3]; b[1]=ls[4]; b[2]=ls[5]; b[3]=ls[6];
            b[4]=ls[7]; b[5]=ls[8]; b[6]=ls[9]; b[7]=ls[10];
        } else {
            b[0]=ls[11]; b[1]=ls[12]; b[2]=0; b[3]=0;
            b[4]=0; b[5]=0; b[6]=0; b[7]=0;
        }
        bfrag[nt] = b;
    }

    float mu[8];
#pragma unroll
    for (int i = 0; i < 8; ++i) mu[i] = 0.0f;

    // ---- main loop: 32 h-tiles; A-frag + w2 shared across 8 n-tile MFMAs ----
#pragma unroll 2
    for (int t = 0; t < 32; ++t) {
        const short8 a = *(const short8*)&Als[(t * 16 + m) * 40 + q * 8];
        const f32x4 wv = *(const f32x4*)&w2s[t * 16 + q * 4];
#pragma unroll
        for (int nt = 0; nt < 8; ++nt) {
            f32x4 c = {0.0f, 0.0f, 0.0f, 0.0f};
            c = __builtin_amdgcn_mfma_f32_16x16x32_bf16(a, bfrag[nt], c, 0, 0, 0);
            // C layout: col n = lane&15, row h = t*16 + q*4 + reg
            mu[nt] = fmaf(fmaxf(c[0], 0.0f), wv[0], mu[nt]);
            mu[nt] = fmaf(fmaxf(c[1], 0.0f), wv[1], mu[nt]);
            mu[nt] = fmaf(fmaxf(c[2], 0.0f), wv[2], mu[nt]);
            mu[nt] = fmaf(fmaxf(c[3], 0.0f), wv[3], mu[nt]);
        }
    }

    // ---- reduce partial mu across quads (butterfly: every lane gets full sum) ----
#pragma unroll
    for (int nt = 0; nt < 8; ++nt) {
        float v = mu[nt];
        v += __shfl_xor(v, 16, 64);
        v += __shfl_xor(v, 32, 64);
        mu[nt] = v;
    }

    // lane stores n = nb + s*64 + lane  (s=0,1) -> needs nt = q + 4s
    float mu0, mu1;
    if (q == 0)      { mu0 = mu[0]; mu1 = mu[4]; }
    else if (q == 1) { mu0 = mu[1]; mu1 = mu[5]; }
    else if (q == 2) { mu0 = mu[2]; mu1 = mu[6]; }
    else             { mu0 = mu[3]; mu1 = mu[7]; }

    int n0 = nb + lane;
    float resid0 = y[n0] - mu0;
    out[(size_t)r * NN + n0] = fmaf(-0.5f * resid0, resid0, NEG_HALF_LOG_2PI);
    int n1 = nb + 64 + lane;
    float resid1 = y[n1] - mu1;
    out[(size_t)r * NN + n1] = fmaf(-0.5f * resid1, resid1, NEG_HALF_LOG_2PI);
}

extern "C" void kernel_launch(void* const* d_in, const int* in_sizes, int n_in,
                              void* d_out, int out_size, void* d_ws, size_t ws_size,
                              hipStream_t stream) {
    const float* x = (const float*)d_in[0];   // [N, 13]
    const float* y = (const float*)d_in[1];   // [N, 1]
    const float* w = (const float*)d_in[2];   // [R, 7168]
    float* out = (float*)d_out;               // [R, N]

    dim3 grid(NN / 512, RR);   // (4, 256) = 1024 blocks, 4 waves each
    dim3 block(NTHREADS);
    ffrelu_mfma_kernel<<<grid, block, 0, stream>>>(x, y, w, out);
}

// Round 7
// 110.616 us; speedup vs baseline: 1.4074x; 1.0003x over previous
//
#include <hip/hip_runtime.h>

#define HH 512
#define IND 13
#define NN 2048
#define RR 256
#define WDIM 7168      // (13+1)*512
#define W1DIM 6656     // 13*512
#define NTHREADS 256
#define NEG_HALF_LOG_2PI (-0.91893853320467274f)

typedef __attribute__((ext_vector_type(8))) short short8;   // 8 bf16 (4 VGPRs) MFMA A/B frag
typedef __attribute__((ext_vector_type(4))) float f32x4;    // MFMA C/D frag

// fp32 -> bf16 round-to-nearest-even (bit pattern)
__device__ __forceinline__ short f2bf(float f) {
    unsigned u = __float_as_uint(f);
    u += 0x7fffu + ((u >> 16) & 1u);
    return (short)(u >> 16);
}
__device__ __forceinline__ float bf2f(short s) {
    return __uint_as_float(((unsigned)(unsigned short)s) << 16);
}

// Per block: one r, 512 n (4 waves x 128 n). Per wave: 32 h-tiles x 8 n-tiles of
// 16x16x32 bf16 MFMA, hidden stays in C-frags, relu+w2-dot in fp32 VALU.
// K packing: A = [w1(13) | w1(13) | 0(6)], B = [x_hi(13) | x_lo(13) | 0(6)]
// => hidden = w1_bf16 . x_fp32 (x split exact); only w1 carries bf16 rounding.
__global__ __launch_bounds__(NTHREADS, 3)
void ffrelu_mfma_kernel(const float* __restrict__ x,
                        const float* __restrict__ y,
                        const float* __restrict__ w,
                        float* __restrict__ out) {
    // w1 rows: 32 bf16 k-slots + 8 pad shorts -> stride 40 shorts (80 B, bank-uniform)
    __shared__ short Als[HH * 40];   // 40 KB
    __shared__ float w2s[HH];        // 2 KB, kept fp32

    const int tid = threadIdx.x;
    const int r = blockIdx.y;
    const int wave = tid >> 6;
    const int lane = tid & 63;
    const int m = lane & 15;        // MFMA row/col index within 16
    const int q = lane >> 4;        // quad 0..3

    const float* wr = w + (size_t)r * WDIM;

    // ---- zero A (k-pad slots 26..31 must be 0), then stage w1 (bf16, k-duplicated) + w2 (fp32) ----
    int* Ai = (int*)Als;
    for (int g = tid; g < HH * 20; g += NTHREADS) Ai[g] = 0;
    __syncthreads();
    for (int g = tid; g < W1DIM; g += NTHREADS) {
        int h = g / IND;
        int i = g - h * IND;
        short b = f2bf(wr[g]);
        Als[h * 40 + i] = b;        // k = i       (pairs with x_hi)
        Als[h * 40 + 13 + i] = b;   // k = 13 + i  (pairs with x_lo)
    }
    for (int g = tid; g < HH; g += NTHREADS) w2s[g] = wr[W1DIM + g];
    __syncthreads();

    // ---- build 8 B-frags from x (hi/lo split), register-resident for whole kernel ----
    const int nb = blockIdx.x * 512 + wave * 128;
    short8 bfrag[8];
#pragma unroll
    for (int nt = 0; nt < 8; ++nt) {
        const float* xp = x + (size_t)(nb + nt * 16 + m) * IND;
        float v[13]; short hs[13], ls[13];
#pragma unroll
        for (int i = 0; i < 13; ++i) {
            v[i] = xp[i];
            hs[i] = f2bf(v[i]);
            ls[i] = f2bf(v[i] - bf2f(hs[i]));
        }
        short8 b;
        if (q == 0) {
            b[0]=hs[0]; b[1]=hs[1]; b[2]=hs[2]; b[3]=hs[3];
            b[4]=hs[4]; b[5]=hs[5]; b[6]=hs[6]; b[7]=hs[7];
        } else if (q == 1) {
            b[0]=hs[8]; b[1]=hs[9]; b[2]=hs[10]; b[3]=hs[11];
            b[4]=hs[12]; b[5]=ls[0]; b[6]=ls[1]; b[7]=ls[2];
        } else if (q == 2) {
            b[0]=ls[3]; b[1]=ls[4]; b[2]=ls[5]; b[3]=ls[6];
            b[4]=ls[7]; b[5]=ls[8]; b[6]=ls[9]; b[7]=ls[10];
        } else {
            b[0]=ls[11]; b[1]=ls[12]; b[2]=0; b[3]=0;
            b[4]=0; b[5]=0; b[6]=0; b[7]=0;
        }
        bfrag[nt] = b;
    }

    float mu[8];
#pragma unroll
    for (int i = 0; i < 8; ++i) mu[i] = 0.0f;

    // ---- main loop: 32 h-tiles; A-frag + w2 shared across 8 n-tile MFMAs ----
#pragma unroll 2
    for (int t = 0; t < 32; ++t) {
        const short8 a = *(const short8*)&Als[(t * 16 + m) * 40 + q * 8];
        const f32x4 wv = *(const f32x4*)&w2s[t * 16 + q * 4];
#pragma unroll
        for (int nt = 0; nt < 8; ++nt) {
            f32x4 c = {0.0f, 0.0f, 0.0f, 0.0f};
            c = __builtin_amdgcn_mfma_f32_16x16x32_bf16(a, bfrag[nt], c, 0, 0, 0);
            // C layout: col n = lane&15, row h = t*16 + q*4 + reg
            mu[nt] = fmaf(fmaxf(c[0], 0.0f), wv[0], mu[nt]);
            mu[nt] = fmaf(fmaxf(c[1], 0.0f), wv[1], mu[nt]);
            mu[nt] = fmaf(fmaxf(c[2], 0.0f), wv[2], mu[nt]);
            mu[nt] = fmaf(fmaxf(c[3], 0.0f), wv[3], mu[nt]);
        }
    }

    // ---- reduce partial mu across quads (butterfly: every lane gets full sum) ----
#pragma unroll
    for (int nt = 0; nt < 8; ++nt) {
        float v = mu[nt];
        v += __shfl_xor(v, 16, 64);
        v += __shfl_xor(v, 32, 64);
        mu[nt] = v;
    }

    // lane stores n = nb + s*64 + lane  (s=0,1) -> needs nt = q + 4s
    float mu0, mu1;
    if (q == 0)      { mu0 = mu[0]; mu1 = mu[4]; }
    else if (q == 1) { mu0 = mu[1]; mu1 = mu[5]; }
    else if (q == 2) { mu0 = mu[2]; mu1 = mu[6]; }
    else             { mu0 = mu[3]; mu1 = mu[7]; }

    int n0 = nb + lane;
    float resid0 = y[n0] - mu0;
    out[(size_t)r * NN + n0] = fmaf(-0.5f * resid0, resid0, NEG_HALF_LOG_2PI);
    int n1 = nb + 64 + lane;
    float resid1 = y[n1] - mu1;
    out[(size_t)r * NN + n1] = fmaf(-0.5f * resid1, resid1, NEG_HALF_LOG_2PI);
}

extern "C" void kernel_launch(void* const* d_in, const int* in_sizes, int n_in,
                              void* d_out, int out_size, void* d_ws, size_t ws_size,
                              hipStream_t stream) {
    const float* x = (const float*)d_in[0];   // [N, 13]
    const float* y = (const float*)d_in[1];   // [N, 1]
    const float* w = (const float*)d_in[2];   // [R, 7168]
    float* out = (float*)d_out;               // [R, N]

    dim3 grid(NN / 512, RR);   // (4, 256) = 1024 blocks, 4 waves each
    dim3 block(NTHREADS);
    ffrelu_mfma_kernel<<<grid, block, 0, stream>>>(x, y, w, out);
}

// Round 8
// 109.009 us; speedup vs baseline: 1.4281x; 1.0147x over previous
//
#include <hip/hip_runtime.h>

#define HH 512
#define IND 13
#define NN 2048
#define RR 256
#define WDIM 7168      // (13+1)*512
#define W1DIM 6656     // 13*512
#define NTHREADS 256
#define NEG_HALF_LOG_2PI (-0.91893853320467274f)

typedef __attribute__((ext_vector_type(8))) short short8;   // 8 bf16 (4 VGPRs) MFMA A/B frag
typedef __attribute__((ext_vector_type(4))) float f32x4;    // MFMA C/D frag

// fp32 -> bf16 round-to-nearest-even (bit pattern)
__device__ __forceinline__ short f2bf(float f) {
    unsigned u = __float_as_uint(f);
    u += 0x7fffu + ((u >> 16) & 1u);
    return (short)(u >> 16);
}
__device__ __forceinline__ float bf2f(short s) {
    return __uint_as_float(((unsigned)(unsigned short)s) << 16);
}

// Per block: one r, 512 n (4 waves x 128 n). Per wave: 32 h-tiles x 8 n-tiles of
// 16x16x32 bf16 MFMA, hidden stays in C-frags, relu+w2-dot in fp32 VALU.
// K packing: A = [w1(13) | w1(13) | 0(6)], B = [x_hi(13) | x_lo(13) | 0(6)]
// => hidden = w1_bf16 . x_fp32 (x split exact); only w1 carries bf16 rounding.
// R8 delta vs green R2/R7 (ONLY change): A-row stride 40 -> 32 shorts (64 B).
// a-frag dword = (m&1)*16 + q*4 + phase: 8 banks/phase, one address each,
// broadcast to 8 lanes -> exactly conflict-free. LDS 43008 -> 34816 B
// -> 4 blocks/CU -> grid 1024 = one clean round (was 768+256 ragged tail).
__global__ __launch_bounds__(NTHREADS, 3)
void ffrelu_mfma_kernel(const float* __restrict__ x,
                        const float* __restrict__ y,
                        const float* __restrict__ w,
                        float* __restrict__ out) {
    __shared__ short Als[HH * 32];   // 32768 B
    __shared__ float w2s[HH];        // 2048 B, kept fp32

    const int tid = threadIdx.x;
    const int r = blockIdx.y;
    const int wave = tid >> 6;
    const int lane = tid & 63;
    const int m = lane & 15;        // MFMA row/col index within 16
    const int q = lane >> 4;        // quad 0..3

    const float* wr = w + (size_t)r * WDIM;

    // ---- zero A (k-pad slots 26..31 must be 0), then stage w1 (bf16, k-duplicated) + w2 (fp32) ----
    int* Ai = (int*)Als;
    for (int g = tid; g < HH * 16; g += NTHREADS) Ai[g] = 0;
    __syncthreads();
    for (int g = tid; g < W1DIM; g += NTHREADS) {
        int h = g / IND;
        int i = g - h * IND;
        short b = f2bf(wr[g]);
        Als[h * 32 + i] = b;        // k = i       (pairs with x_hi)
        Als[h * 32 + 13 + i] = b;   // k = 13 + i  (pairs with x_lo)
    }
    for (int g = tid; g < HH; g += NTHREADS) w2s[g] = wr[W1DIM + g];
    __syncthreads();

    // ---- build 8 B-frags from x (hi/lo split), register-resident for whole kernel ----
    const int nb = blockIdx.x * 512 + wave * 128;
    short8 bfrag[8];
#pragma unroll
    for (int nt = 0; nt < 8; ++nt) {
        const float* xp = x + (size_t)(nb + nt * 16 + m) * IND;
        float v[13]; short hs[13], ls[13];
#pragma unroll
        for (int i = 0; i < 13; ++i) {
            v[i] = xp[i];
            hs[i] = f2bf(v[i]);
            ls[i] = f2bf(v[i] - bf2f(hs[i]));
        }
        short8 b;
        if (q == 0) {
            b[0]=hs[0]; b[1]=hs[1]; b[2]=hs[2]; b[3]=hs[3];
            b[4]=hs[4]; b[5]=hs[5]; b[6]=hs[6]; b[7]=hs[7];
        } else if (q == 1) {
            b[0]=hs[8]; b[1]=hs[9]; b[2]=hs[10]; b[3]=hs[11];
            b[4]=hs[12]; b[5]=ls[0]; b[6]=ls[1]; b[7]=ls[2];
        } else if (q == 2) {
            b[0]=ls[3]; b[1]=ls[4]; b[2]=ls[5]; b[3]=ls[6];
            b[4]=ls[7]; b[5]=ls[8]; b[6]=ls[9]; b[7]=ls[10];
        } else {
            b[0]=ls[11]; b[1]=ls[12]; b[2]=0; b[3]=0;
            b[4]=0; b[5]=0; b[6]=0; b[7]=0;
        }
        bfrag[nt] = b;
    }

    float mu[8];
#pragma unroll
    for (int i = 0; i < 8; ++i) mu[i] = 0.0f;

    // ---- main loop: 32 h-tiles; A-frag + w2 shared across 8 n-tile MFMAs ----
#pragma unroll 2
    for (int t = 0; t < 32; ++t) {
        const short8 a = *(const short8*)&Als[(t * 16 + m) * 32 + q * 8];
        const f32x4 wv = *(const f32x4*)&w2s[t * 16 + q * 4];
#pragma unroll
        for (int nt = 0; nt < 8; ++nt) {
            f32x4 c = {0.0f, 0.0f, 0.0f, 0.0f};
            c = __builtin_amdgcn_mfma_f32_16x16x32_bf16(a, bfrag[nt], c, 0, 0, 0);
            // C layout: col n = lane&15, row h = t*16 + q*4 + reg
            mu[nt] = fmaf(fmaxf(c[0], 0.0f), wv[0], mu[nt]);
            mu[nt] = fmaf(fmaxf(c[1], 0.0f), wv[1], mu[nt]);
            mu[nt] = fmaf(fmaxf(c[2], 0.0f), wv[2], mu[nt]);
            mu[nt] = fmaf(fmaxf(c[3], 0.0f), wv[3], mu[nt]);
        }
    }

    // ---- reduce partial mu across quads (butterfly: every lane gets full sum) ----
#pragma unroll
    for (int nt = 0; nt < 8; ++nt) {
        float v = mu[nt];
        v += __shfl_xor(v, 16, 64);
        v += __shfl_xor(v, 32, 64);
        mu[nt] = v;
    }

    // lane stores n = nb + s*64 + lane  (s=0,1) -> needs nt = q + 4s
    float mu0, mu1;
    if (q == 0)      { mu0 = mu[0]; mu1 = mu[4]; }
    else if (q == 1) { mu0 = mu[1]; mu1 = mu[5]; }
    else if (q == 2) { mu0 = mu[2]; mu1 = mu[6]; }
    else             { mu0 = mu[3]; mu1 = mu[7]; }

    int n0 = nb + lane;
    float resid0 = y[n0] - mu0;
    out[(size_t)r * NN + n0] = fmaf(-0.5f * resid0, resid0, NEG_HALF_LOG_2PI);
    int n1 = nb + 64 + lane;
    float resid1 = y[n1] - mu1;
    out[(size_t)r * NN + n1] = fmaf(-0.5f * resid1, resid1, NEG_HALF_LOG_2PI);
}

extern "C" void kernel_launch(void* const* d_in, const int* in_sizes, int n_in,
                              void* d_out, int out_size, void* d_ws, size_t ws_size,
                              hipStream_t stream) {
    const float* x = (const float*)d_in[0];   // [N, 13]
    const float* y = (const float*)d_in[1];   // [N, 1]
    const float* w = (const float*)d_in[2];   // [R, 7168]
    float* out = (float*)d_out;               // [R, N]

    dim3 grid(NN / 512, RR);   // (4, 256) = 1024 blocks, 4 waves each
    dim3 block(NTHREADS);
    ffrelu_mfma_kernel<<<grid, block, 0, stream>>>(x, y, w, out);
}